// Round 12
// baseline (324.258 us; speedup 1.0000x reference)
//
#include <hip/hip_runtime.h>
#include <cstddef>

#define D_MODEL 1024
#define NH 16
#define HD 64
#define BATCH 4
#define SEQ 2048
#define MTOT (BATCH * SEQ)  // 8192

typedef _Float16 half8 __attribute__((ext_vector_type(8)));
typedef _Float16 half4v __attribute__((ext_vector_type(4)));
typedef float f32x4 __attribute__((ext_vector_type(4)));

#if __has_builtin(__builtin_amdgcn_exp2f)
#define EXP2(x) __builtin_amdgcn_exp2f(x)
#else
#define EXP2(x) __expf((x)*0.69314718056f)
#endif

// ---------------------------------------------------------------------------
// Fused prep: blocks 0..255 x-cvt; 256..1279 weight transposes (r9 proven).
// ---------------------------------------------------------------------------
__global__ __launch_bounds__(256) void prep(
    const float* __restrict__ x, _Float16* __restrict__ xh,
    const float* __restrict__ W0, const float* __restrict__ W1,
    const float* __restrict__ W2, const float* __restrict__ W3,
    _Float16* __restrict__ T0, _Float16* __restrict__ T1,
    _Float16* __restrict__ T2, _Float16* __restrict__ T3)
{
    __shared__ float T[64][65];
    const int bid = blockIdx.x;
    if (bid < 256) {
        const size_t base = (size_t)bid * 4096 + threadIdx.x;
#pragma unroll
        for (int it = 0; it < 16; ++it) {
            const size_t i = base + (size_t)it * 256;
            const float4* p = (const float4*)x + 2 * i;
            float4 a = p[0], b = p[1];
            half8 h;
            h[0] = (_Float16)a.x; h[1] = (_Float16)a.y; h[2] = (_Float16)a.z; h[3] = (_Float16)a.w;
            h[4] = (_Float16)b.x; h[5] = (_Float16)b.y; h[6] = (_Float16)b.z; h[7] = (_Float16)b.w;
            *((half8*)xh + i) = h;
        }
    } else {
        const int t = bid - 256;
        const int mtx = t >> 8;
        const float* W = (mtx == 0) ? W0 : (mtx == 1) ? W1 : (mtx == 2) ? W2 : W3;
        _Float16*   Wt = (mtx == 0) ? T0 : (mtx == 1) ? T1 : (mtx == 2) ? T2 : T3;
        const int tile = t & 255;
        const int k0 = (tile >> 4) * 64, n0 = (tile & 15) * 64;
        const int r = threadIdx.x >> 4, c4 = (threadIdx.x & 15) * 4;

#pragma unroll
        for (int i = 0; i < 4; ++i) {
            float4 v = *(const float4*)(W + (size_t)(k0 + r + 16 * i) * 1024 + n0 + c4);
            T[r + 16 * i][c4 + 0] = v.x; T[r + 16 * i][c4 + 1] = v.y;
            T[r + 16 * i][c4 + 2] = v.z; T[r + 16 * i][c4 + 3] = v.w;
        }
        __syncthreads();
#pragma unroll
        for (int i = 0; i < 4; ++i) {
            const int n = r + 16 * i;
            half4v h;
            h[0] = (_Float16)T[c4 + 0][n]; h[1] = (_Float16)T[c4 + 1][n];
            h[2] = (_Float16)T[c4 + 2][n]; h[3] = (_Float16)T[c4 + 3][n];
            *(half4v*)(Wt + (size_t)(n0 + n) * 1024 + k0 + c4) = h;
        }
    }
}

// ---------------------------------------------------------------------------
// Flatmm-hybrid MFMA GEMM: wave-exclusive A-rows read DIRECTLY from global
// (no LDS staging, no duplication — the barrier no longer couples A), only
// the 64-wide B panel staged in LDS (9.2 KB, shared by all 4 waves).
// Per wave-ktile: 32 MFMAs over just 12 LDS ops (vs 24 in the r8 core).
// BMW = rows per wave (64 -> BM=256 QKV @3 blocks/CU; 32 -> BM=128 O-proj
// @4 blocks/CU with 1024 blocks — residency AND full density).
// XCD-affinity 1D grid: y = L % MB -> L%8 = y%8 -> A-slice L2-resident.
// QKV=1: c_=L/32: z = c_>>4, xb = c_&15 (BN=64 = one head).
//        z in {0,1}: f16 [bh][s][hd]; z==2: V transposed [bh][d][s].
// QKV=0: f32 [m][n] + bias.
// ---------------------------------------------------------------------------
template <int QKV, int BMW>
__global__ __launch_bounds__(256, (BMW == 64) ? 3 : 4) void gemm_flat(
    const _Float16* __restrict__ A,
    const _Float16* __restrict__ Bt0, const _Float16* __restrict__ Bt1, const _Float16* __restrict__ Bt2,
    const float* __restrict__ bi0, const float* __restrict__ bi1, const float* __restrict__ bi2,
    void* __restrict__ C0, void* __restrict__ C1, void* __restrict__ C2)
{
    constexpr int NI = BMW / 16;          // A-frags / acc rows per wave
    constexpr int MB = QKV ? 32 : 64;     // m-blocks in grid

    const int L  = blockIdx.x;
    const int y  = L & (MB - 1);
    const int c_ = L / MB;
    const int z  = QKV ? (c_ >> 4) : 0;
    const int xb = QKV ? (c_ & 15) : c_;

    const _Float16* Bt = (z == 0) ? Bt0 : (z == 1) ? Bt1 : Bt2;
    const float*   bia = (z == 0) ? bi0 : (z == 1) ? bi1 : bi2;
    void*            C = (z == 0) ? C0  : (z == 1) ? C1  : C2;

    __shared__ _Float16 Bs[64][72];       // 9216 B

    const int tid  = threadIdx.x;
    const int w    = tid >> 6;
    const int lane = tid & 63;
    const int l15  = lane & 15;
    const int lg   = lane >> 4;
    const int m0 = y * (4 * BMW);
    const int n0 = xb * 64;

    const int srow = tid >> 3;            // B staging row (+32 for j=1)
    const int scol = (tid & 7) * 8;

    const _Float16* Bb = Bt + (size_t)(n0 + srow) * 1024 + scol;
    const _Float16* Aw = A + (size_t)(m0 + w * BMW + l15) * 1024 + 8 * lg;

    half8 bR[2];
#pragma unroll
    for (int j = 0; j < 2; ++j)
        bR[j] = *(const half8*)(Bb + (size_t)(32 * j) * 1024);

    f32x4 acc[NI][4];
#pragma unroll
    for (int i = 0; i < NI; ++i)
#pragma unroll
        for (int j = 0; j < 4; ++j) { acc[i][j][0] = 0.f; acc[i][j][1] = 0.f; acc[i][j][2] = 0.f; acc[i][j][3] = 0.f; }

    for (int kt = 0; kt < 16; ++kt) {
        const int k0 = kt * 64;
        __syncthreads();
#pragma unroll
        for (int j = 0; j < 2; ++j)
            *(half8*)&Bs[srow + 32 * j][scol] = bR[j];
        __syncthreads();
        if (kt < 15) {
#pragma unroll
            for (int j = 0; j < 2; ++j)
                bR[j] = *(const half8*)(Bb + (size_t)(32 * j) * 1024 + k0 + 64);
        }

        // A fragments direct from global (wave-exclusive rows, L2-resident)
        half8 af[NI][2];
#pragma unroll
        for (int i = 0; i < NI; ++i)
#pragma unroll
            for (int c = 0; c < 2; ++c)
                af[i][c] = *(const half8*)(Aw + (size_t)(16 * i) * 1024 + k0 + 32 * c);

        half8 bf[4][2];
#pragma unroll
        for (int j = 0; j < 4; ++j)
#pragma unroll
            for (int c = 0; c < 2; ++c)
                bf[j][c] = *(const half8*)&Bs[16 * j + l15][32 * c + 8 * lg];

#pragma unroll
        for (int c = 0; c < 2; ++c)
#pragma unroll
            for (int i = 0; i < NI; ++i)
#pragma unroll
                for (int j = 0; j < 4; ++j)
                    acc[i][j] = __builtin_amdgcn_mfma_f32_16x16x32_f16(af[i][c], bf[j][c], acc[i][j], 0, 0, 0);
    }

    float bv[4];
#pragma unroll
    for (int j = 0; j < 4; ++j) bv[j] = bia[n0 + 16 * j + l15];

#pragma unroll
    for (int i = 0; i < NI; ++i)
#pragma unroll
        for (int j = 0; j < 4; ++j)
#pragma unroll
            for (int r = 0; r < 4; ++r) {
                const int m = m0 + w * BMW + 16 * i + 4 * lg + r;
                const int n = n0 + 16 * j + l15;
                const float val = acc[i][j][r] + bv[j];
                if (QKV) {
                    const int bb = m >> 11, ss = m & 2047, hd = n & 63;
                    if (z < 2)   // Q, K: [bh][s][hd]
                        ((_Float16*)C)[((size_t)(bb * NH + xb) * SEQ + ss) * HD + hd] = (_Float16)val;
                    else         // V: transposed [bh][d][s]
                        ((_Float16*)C)[((size_t)(bb * NH + xb) * HD + hd) * SEQ + ss] = (_Float16)val;
                } else {
                    ((float*)C)[(size_t)m * 1024 + n] = val;
                }
            }
}

// ---------------------------------------------------------------------------
// Causal flash attention v4b (round-9/11 proven, unchanged): LDS-staged K
// and V, 64-row q-tiles paired for uniform work (33 ktiles/block), grid
// (16, B*NH) = 1024 blocks, 30 KB LDS -> 4/CU, exp2-domain no-max softmax.
// Vt pre-transposed [bh][d][s]. Pitch-80 LDS.
// ---------------------------------------------------------------------------
__global__ __launch_bounds__(256, 4) void attn_fwd_mfma(
    const _Float16* __restrict__ Q, const _Float16* __restrict__ K,
    const _Float16* __restrict__ Vt, _Float16* __restrict__ O)
{
    __shared__ _Float16 Ks[64][80];
    __shared__ _Float16 Vs[64][80];
    __shared__ _Float16 Ps[4][16][80];

    const int tid  = threadIdx.x;
    const int w    = tid >> 6;
    const int lane = tid & 63;
    const int l15  = lane & 15;
    const int lg   = lane >> 4;

    const int bh = blockIdx.y;
    const int b  = bh >> 4, h = bh & 15;

    const _Float16* Qb  = Q  + (size_t)bh * SEQ * HD;
    const _Float16* Kb  = K  + (size_t)bh * SEQ * HD;   // [s][d]
    const _Float16* Vtb = Vt + (size_t)bh * HD * SEQ;   // [d][s]

    const int srow = tid >> 3;
    const int scol = (tid & 7) * 8;

    for (int pass = 0; pass < 2; ++pass) {
        const int qt = pass ? (int)blockIdx.x : (31 - (int)blockIdx.x);
        const int q0 = qt * 64;
        const int ntiles = qt + 1;

        half8 qa[2];
        {
            const _Float16* qp = Qb + (size_t)(q0 + 16 * w + l15) * HD + 8 * lg;
            qa[0] = *(const half8*)(qp);
            qa[1] = *(const half8*)(qp + 32);
#pragma unroll
            for (int c = 0; c < 2; ++c)
#pragma unroll
                for (int j = 0; j < 8; ++j)
                    qa[c][j] = (_Float16)((float)qa[c][j] * 0.18033688f);
        }

        f32x4 o_[4];
#pragma unroll
        for (int ft = 0; ft < 4; ++ft) { o_[ft][0] = 0.f; o_[ft][1] = 0.f; o_[ft][2] = 0.f; o_[ft][3] = 0.f; }
        float lp[4] = {0.f, 0.f, 0.f, 0.f};

        half8 kreg[2], vreg[2];
#pragma unroll
        for (int j = 0; j < 2; ++j) {
            kreg[j] = *(const half8*)(Kb  + (size_t)(srow + 32 * j) * HD + scol);
            vreg[j] = *(const half8*)(Vtb + (size_t)(srow + 32 * j) * SEQ + scol);
        }

        for (int kt = 0; kt < ntiles; ++kt) {
            __syncthreads();
#pragma unroll
            for (int j = 0; j < 2; ++j) {
                *(half8*)&Ks[srow + 32 * j][scol] = kreg[j];
                *(half8*)&Vs[srow + 32 * j][scol] = vreg[j];
            }
            __syncthreads();

            if (kt + 1 < ntiles) {
                const int k0 = (kt + 1) * 64;
#pragma unroll
                for (int j = 0; j < 2; ++j) {
                    kreg[j] = *(const half8*)(Kb  + (size_t)(k0 + srow + 32 * j) * HD + scol);
                    vreg[j] = *(const half8*)(Vtb + (size_t)(srow + 32 * j) * SEQ + k0 + scol);
                }
            }

            // ---- S = Q K^T : 8 MFMAs ----
            f32x4 s[4];
#pragma unroll
            for (int f = 0; f < 4; ++f) { s[f][0] = 0.f; s[f][1] = 0.f; s[f][2] = 0.f; s[f][3] = 0.f; }
#pragma unroll
            for (int c = 0; c < 2; ++c)
#pragma unroll
                for (int f = 0; f < 4; ++f) {
                    half8 kb = *(const half8*)&Ks[16 * f + l15][32 * c + 8 * lg];
                    s[f] = __builtin_amdgcn_mfma_f32_16x16x32_f16(qa[c], kb, s[f], 0, 0, 0);
                }

            // ---- p = exp2(s), diagonal mask, stash to Ps ----
            const bool dg = (kt == qt);
#pragma unroll
            for (int f = 0; f < 4; ++f)
#pragma unroll
                for (int r = 0; r < 4; ++r) {
                    float p = EXP2(s[f][r]);
                    if (dg && (16 * f + l15 > 16 * w + 4 * lg + r)) p = 0.f;
                    lp[r] += p;
                    Ps[w][4 * lg + r][16 * f + l15] = (_Float16)p;
                }

            // ---- O += P V : 8 MFMAs ----
            half8 pa[2];
            pa[0] = *(const half8*)&Ps[w][l15][8 * lg];
            pa[1] = *(const half8*)&Ps[w][l15][32 + 8 * lg];
#pragma unroll
            for (int c = 0; c < 2; ++c)
#pragma unroll
                for (int ft = 0; ft < 4; ++ft) {
                    half8 vb = *(const half8*)&Vs[16 * ft + l15][32 * c + 8 * lg];
                    o_[ft] = __builtin_amdgcn_mfma_f32_16x16x32_f16(pa[c], vb, o_[ft], 0, 0, 0);
                }
        }

        // ---- epilogue ----
#pragma unroll
        for (int r = 0; r < 4; ++r) {
            float rs = lp[r];
            rs += __shfl_xor(rs, 1);
            rs += __shfl_xor(rs, 2);
            rs += __shfl_xor(rs, 4);
            rs += __shfl_xor(rs, 8);
            const float inv = 1.0f / rs;
            _Float16* orow = O + (size_t)(b * SEQ + q0 + 16 * w + 4 * lg + r) * D_MODEL + h * HD + l15;
#pragma unroll
            for (int ft = 0; ft < 4; ++ft) orow[16 * ft] = (_Float16)(o_[ft][r] * inv);
        }
        __syncthreads();  // Ks/Vs/Ps reuse across passes
    }
}

// ---------------------------------------------------------------------------
extern "C" void kernel_launch(void* const* d_in, const int* in_sizes, int n_in,
                              void* d_out, int out_size, void* d_ws, size_t ws_size,
                              hipStream_t stream)
{
    const float* x  = (const float*)d_in[0];
    const float* wq = (const float*)d_in[1];
    const float* bq = (const float*)d_in[2];
    const float* wk = (const float*)d_in[3];
    const float* bk = (const float*)d_in[4];
    const float* wv = (const float*)d_in[5];
    const float* bv = (const float*)d_in[6];
    const float* wo = (const float*)d_in[7];
    const float* bo = (const float*)d_in[8];
    float* out = (float*)d_out;

    const size_t SZ = (size_t)MTOT * D_MODEL;  // 8388608
    const size_t WZ = (size_t)D_MODEL * D_MODEL;

    _Float16* xh  = (_Float16*)d_ws;
    _Float16* wtq = xh + SZ;
    _Float16* wtk = wtq + WZ;
    _Float16* wtv = wtk + WZ;
    _Float16* wto = wtv + WZ;
    _Float16* Qh  = wto + WZ;
    _Float16* Kh  = Qh + SZ;
    _Float16* Vtg = Kh + SZ;   // V, already transposed [bh][d][s]
    _Float16* AOh = Vtg + SZ;  // total ~88 MiB

    // fused prep: x cvt (blocks 0..255) + 4 weight transposes (256..1279)
    prep<<<dim3(1280), 256, 0, stream>>>(x, xh, wq, wk, wv, wo, wtq, wtk, wtv, wto);
    // QKV: flat-hybrid, BM=256 (BMW=64), 32 m-blocks x 48 (z,head) = 1536
    gemm_flat<1, 64><<<dim3(1536), 256, 0, stream>>>(xh, wtq, wtk, wtv, bq, bk, bv, Qh, Kh, Vtg);
    // attention (round-9/11 proven v4b)
    attn_fwd_mfma<<<dim3(16, BATCH * NH), 256, 0, stream>>>(Qh, Kh, Vtg, AOh);
    // O-proj: flat-hybrid, BM=128 (BMW=32), 64 m-blocks x 16 heads = 1024
    gemm_flat<0, 32><<<dim3(1024), 256, 0, stream>>>(AOh, wto, wto, wto, bo, bo, bo, out, out, out);
}